// Round 4
// baseline (216.179 us; speedup 1.0000x reference)
//
#include <hip/hip_runtime.h>

typedef __bf16 bf16;
typedef __attribute__((ext_vector_type(8))) __bf16 bf16x8;
typedef __attribute__((ext_vector_type(4))) __bf16 bf16x4;
typedef __attribute__((ext_vector_type(4))) float f32x4;

#define MFMA16(A, B, C) __builtin_amdgcn_mfma_f32_16x16x32_bf16(A, B, C, 0, 0, 0)

// ---------------------------------------------------------------------------
// k_prep: weight bf16 conversion, yu bilinear upsample, gating coefficients
// grid = 232 blocks x 256
// ---------------------------------------------------------------------------
__global__ __launch_bounds__(256) void k_prep(
    const float* __restrict__ y, const float* __restrict__ wy, const float* __restrict__ by,
    const float* __restrict__ wq, const float* __restrict__ bq,
    const float* __restrict__ wk, const float* __restrict__ bk,
    const float* __restrict__ wv,
    bf16* __restrict__ wq_bf, bf16* __restrict__ wk_bf, bf16* __restrict__ wv_bf,
    float* __restrict__ yu, float* __restrict__ aq, float* __restrict__ cq,
    float* __restrict__ ak, float* __restrict__ ck)
{
  int blk = blockIdx.x, t = threadIdx.x;
  if (blk < 192) {
    int idx4 = blk * 256 + t;
    int fo = idx4 * 4;
    const float* src; bf16* dst; int off;
    if (fo < 65536)       { src = wq; dst = wq_bf; off = fo; }
    else if (fo < 131072) { src = wk; dst = wk_bf; off = fo - 65536; }
    else                  { src = wv; dst = wv_bf; off = fo - 131072; }
    float4 v = *(const float4*)(src + off);
    bf16x4 o;
    o[0] = (bf16)v.x; o[1] = (bf16)v.y; o[2] = (bf16)v.z; o[3] = (bf16)v.w;
    *(bf16x4*)(dst + off) = o;
  } else if (blk < 200) {
    // bilinear upsample y[b,1,24,24] -> yu[b,96,96], half-pixel, edge clamp
    int b = blk - 192;
    const float* yb = y + b * 576;
#pragma unroll 1
    for (int i = 0; i < 36; ++i) {
      int e = t + i * 256;
      int oh = e / 96, ow = e % 96;
      float sh = oh * 0.25f - 0.375f;
      float sw = ow * 0.25f - 0.375f;
      int ih0 = (int)floorf(sh);
      int iw0 = (int)floorf(sw);
      float fh = sh - (float)ih0, fw = sw - (float)iw0;
      int ih0c = min(23, max(0, ih0)), ih1c = min(23, max(0, ih0 + 1));
      int iw0c = min(23, max(0, iw0)), iw1c = min(23, max(0, iw0 + 1));
      float v00 = yb[ih0c * 24 + iw0c], v01 = yb[ih0c * 24 + iw1c];
      float v10 = yb[ih1c * 24 + iw0c], v11 = yb[ih1c * 24 + iw1c];
      yu[b * 9216 + e] = (1.0f - fh) * ((1.0f - fw) * v00 + fw * v01)
                       + fh * ((1.0f - fw) * v10 + fw * v11);
    }
  } else {
    // gate coefficients: aq = wq*wy, cq = wq*by + bq (same for k)
    int ol = t >> 5, cl = t & 31;
    int o = (blk - 200) * 8 + ol;
    int c0 = cl * 8;
    float4 wy0 = *(const float4*)(wy + c0), wy1 = *(const float4*)(wy + c0 + 4);
    float4 by0 = *(const float4*)(by + c0), by1 = *(const float4*)(by + c0 + 4);
    float4 q0  = *(const float4*)(wq + o * 256 + c0), q1 = *(const float4*)(wq + o * 256 + c0 + 4);
    float4 k0  = *(const float4*)(wk + o * 256 + c0), k1 = *(const float4*)(wk + o * 256 + c0 + 4);
    float wyv[8] = {wy0.x, wy0.y, wy0.z, wy0.w, wy1.x, wy1.y, wy1.z, wy1.w};
    float byv[8] = {by0.x, by0.y, by0.z, by0.w, by1.x, by1.y, by1.z, by1.w};
    float qv[8]  = {q0.x, q0.y, q0.z, q0.w, q1.x, q1.y, q1.z, q1.w};
    float kv[8]  = {k0.x, k0.y, k0.z, k0.w, k1.x, k1.y, k1.z, k1.w};
    float saq = 0.f, scq = 0.f, sak = 0.f, sck = 0.f;
#pragma unroll
    for (int j = 0; j < 8; ++j) {
      saq += qv[j] * wyv[j]; scq += qv[j] * byv[j];
      sak += kv[j] * wyv[j]; sck += kv[j] * byv[j];
    }
#pragma unroll
    for (int s = 16; s >= 1; s >>= 1) {
      saq += __shfl_xor(saq, s, 32);
      scq += __shfl_xor(scq, s, 32);
      sak += __shfl_xor(sak, s, 32);
      sck += __shfl_xor(sck, s, 32);
    }
    if (cl == 0) {
      aq[o] = saq; cq[o] = scq + bq[o];
      ak[o] = sak; ck[o] = sck + bk[o];
    }
  }
}

// ---------------------------------------------------------------------------
// k_fused: one block of 1024 threads (16 waves, 4/SIMD) per (b,h) row.
// Each wave owns one 16-row o/d tile. All intermediates on-chip.
//   LDS: xs [96 w][264 c]   50688 B  (reused as vs [96 w][264 d], d-permuted)
//        ks [256 o][104 w]  53248 B
//   Total 103936 B -> 1 block/CU, 16 waves = 4 waves/SIMD.
// R4: (1) q-stage LDS round-trip removed — qf built straight from qacc's
// D[w][o] layout; the contraction-slot permutation pi(g,j)=16(j>>2)+4g+(j&3)
// is applied to BOTH qf (naturally) and the K fragment reads (two b64s,
// shuffled), so QK^T is unchanged; D-layout (and hence PV/V-permute) is
// unaffected. (2) weight loads software-pipelined by one kq (kq=0 issued
// before the phase-0 barrier). (3) direct-store epilogue: lane holds output
// rows otile+4g+r at w=16n+l15 -> 24 scalar f32 stores (64-B runs, L2
// merges); removes 4 barriers + LDS f32 round-trip.
// ---------------------------------------------------------------------------
__global__ __launch_bounds__(1024, 1) void k_fused(
    const float* __restrict__ x, const float* __restrict__ yu,
    const bf16* __restrict__ wq_bf, const bf16* __restrict__ wk_bf, const bf16* __restrict__ wv_bf,
    const float* __restrict__ bq, const float* __restrict__ bk, const float* __restrict__ bv,
    const float* __restrict__ aq, const float* __restrict__ cq,
    const float* __restrict__ ak, const float* __restrict__ ck,
    float* __restrict__ out)
{
  __shared__ __align__(16) bf16 xs[96 * 264];             // 50688 B (-> vs)
  __shared__ __align__(16) bf16 ks[256 * 104];            // 53248 B

  int pl = blockIdx.x;
  int b = pl / 96, h = pl % 96;
  int t = threadIdx.x;
  int wid = t >> 6, lane = t & 63;
  int l15 = lane & 15, g = lane >> 4;
  int otile = wid * 16;            // this wave's 16-row o/d tile base

  // ---- phase 0: load x[b,:,h,:] -> xs[w][c] (bf16) ----
  {
    const float* xrow = x + (size_t)b * 2359296 + (size_t)h * 96;
#pragma unroll
    for (int i = 0; i < 3; ++i) {
      int tsk = i * 1024 + t;       // 96 w x 32 cgroups
      int w = tsk % 96;
      int c0 = (tsk / 96) * 8;
      float v[8];
#pragma unroll
      for (int j = 0; j < 8; ++j) v[j] = xrow[(size_t)(c0 + j) * 9216 + w];
      bf16x8 o8;
#pragma unroll
      for (int j = 0; j < 8; ++j) o8[j] = (bf16)v[j];
      *(bf16x8*)(xs + w * 264 + c0) = o8;
    }
  }

  // weight frags for kq=0 issued before the barrier (latency under sync)
  size_t wo0 = (size_t)(otile + l15) * 256 + g * 8;
  bf16x8 Bq_c = *(const bf16x8*)(wq_bf + wo0);
  bf16x8 Bk_c = *(const bf16x8*)(wk_bf + wo0);
  bf16x8 Bv_c = *(const bf16x8*)(wv_bf + wo0);

  __syncthreads();

  const float SC = 0.17677669529663687f;  // 1/sqrt(32), folded into q

  bf16x8 qf[3];   // this wave's 16 o-rows of q, pi-permuted fragment

  // ---- phase 1: q, k AND v projections in one pass over xs ----
  // Per kq: 6 LDS A-frags + 3 (pipelined) global weight frags -> 18 MFMAs.
  {
    f32x4 qacc[6] = {};
    f32x4 kacc[6] = {};
    f32x4 vacc[6] = {};
#pragma unroll 1
    for (int kq = 0; kq < 8; ++kq) {
      // prefetch next kq's weight frags (independent of this iteration)
      bf16x8 Bq_n, Bk_n, Bv_n;
      if (kq < 7) {
        size_t wo = wo0 + (kq + 1) * 32;
        Bq_n = *(const bf16x8*)(wq_bf + wo);
        Bk_n = *(const bf16x8*)(wk_bf + wo);
        Bv_n = *(const bf16x8*)(wv_bf + wo);
      }
      const bf16* xp = xs + kq * 32 + g * 8;
      bf16x8 A[6];
#pragma unroll
      for (int m = 0; m < 6; ++m)
        A[m] = *(const bf16x8*)(xp + (m * 16 + l15) * 264);
#pragma unroll
      for (int m = 0; m < 6; ++m) {
        qacc[m] = MFMA16(A[m], Bq_c, qacc[m]);     // D[w][o]  (swapped)
        kacc[m] = MFMA16(A[m], Bk_c, kacc[m]);     // D[w][o]  (swapped)
        vacc[m] = MFMA16(Bv_c, A[m], vacc[m]);     // D[d][w]  (natural)
      }
      Bq_c = Bq_n; Bk_c = Bk_n; Bv_c = Bv_n;
    }

    // yu gate values loaded AFTER the MFMA loop (keeps loop VGPR pressure low)
    float4 yv[6];
    {
      const float* yr = yu + (size_t)pl * 96;
#pragma unroll
      for (int mt = 0; mt < 6; ++mt)
        yv[mt] = *(const float4*)(yr + mt * 16 + g * 4);
    }
    int o = otile + l15;
    float bqv = bq[o], aq0 = aq[o], cq0 = cq[o];
    float bkv = bk[o], ak0 = ak[o], ck0 = ck[o];

    // q: gate+scale -> qf DIRECTLY (slot j of chunk kk holds w =
    // 32kk + 16(j>>2) + 4g + (j&3), i.e. qacc[2kk+(j>>2)][j&3]).
#pragma unroll
    for (int kk = 0; kk < 3; ++kk) {
      bf16x8 qq;
#pragma unroll
      for (int jh = 0; jh < 2; ++jh) {
        int m = 2 * kk + jh;
        float yy[4] = {yv[m].x, yv[m].y, yv[m].z, yv[m].w};
#pragma unroll
        for (int r = 0; r < 4; ++r)
          qq[jh * 4 + r] = (bf16)((qacc[m][r] + bqv) * (yy[r] * aq0 + cq0) * SC);
      }
      qf[kk] = qq;
    }

    // k: gate -> ks[o][w] (this wave's 16 rows)
#pragma unroll
    for (int m = 0; m < 6; ++m) {
      float yy[4] = {yv[m].x, yv[m].y, yv[m].z, yv[m].w};
      bf16x4 pk;
#pragma unroll
      for (int r = 0; r < 4; ++r)
        pk[r] = (bf16)((kacc[m][r] + bkv) * (yy[r] * ak0 + ck0));
      *(bf16x4*)(ks + (size_t)o * 104 + m * 16 + g * 4) = pk;
    }

    // v: bias; wait for ALL waves to finish reading xs, then write vs = xs.
    // D-PERMUTED store: d = 32a + dn*16 + g*4 + r placed at
    // pos = 32a + g*8 + dn*4 + r (agrees with pa slot map = pi).
    float4 bm = *(const float4*)(bv + otile + g * 4);
    float bb[4] = {bm.x, bm.y, bm.z, bm.w};
    __syncthreads();   // all xs reads done block-wide
    bf16* vs = xs;     // reuse xs as vs[w][264 dpos]
    int vbase = (otile & ~16) + ((otile >> 2) & 4);   // 32a + dn*4
#pragma unroll
    for (int n = 0; n < 6; ++n) {
      bf16x4 pk;
#pragma unroll
      for (int r = 0; r < 4; ++r) pk[r] = (bf16)(vacc[n][r] + bb[r]);
      *(bf16x4*)(vs + (size_t)(n * 16 + l15) * 264 + vbase + g * 8) = pk;
    }
  }
  __syncthreads();     // ks + vs visible to all waves

  // ---- phase 4: swapped scores -> in-register P -> out = P*v ----
  const bf16* vs = xs;
  f32x4 oacc[6] = {};
  float lp = 0.f;

  // K fragment loader with the pi slot-permutation: slot j of chunk kk =
  // ks[d][32kk + 16(j>>2) + 4g + (j&3)] -> two b64 reads 32 B apart.
  auto load_K = [&](int dt, bf16x8* K) {
    const bf16* kp = ks + (size_t)(dt * 32 + l15) * 104 + g * 4;
#pragma unroll
    for (int kk = 0; kk < 3; ++kk)
#pragma unroll
      for (int dn = 0; dn < 2; ++dn) {
        const bf16* p = kp + (size_t)(dn * 16) * 104 + kk * 32;
        bf16x4 lo = *(const bf16x4*)(p);
        bf16x4 hi = *(const bf16x4*)(p + 16);
        K[kk * 2 + dn] = __builtin_shufflevector(lo, hi, 0, 1, 2, 3, 4, 5, 6, 7);
      }
  };

  bf16x8 KA[6], KB[6];   // K-fragment double-buffer (regs)
  load_K(0, KA);

  auto attn_step = [&](int dt, bf16x8* Kc, bf16x8* Kn, bool pf) {
    int d0 = dt * 32;
    // prefetch next dt's K-fragments (independent; overlaps QK+exp+PV)
    if (pf) load_K(dt + 1, Kn);
    f32x4 s0 = {}, s1 = {};
    __builtin_amdgcn_s_setprio(1);
#pragma unroll
    for (int kk = 0; kk < 3; ++kk) {
      s0 = MFMA16(Kc[kk * 2 + 0], qf[kk], s0);   // D[m=d][n=o]
      s1 = MFMA16(Kc[kk * 2 + 1], qf[kk], s1);
    }
    __builtin_amdgcn_s_setprio(0);
    // lane holds P[o=otile+l15][d0 + dn*16 + g*4 + r] -> pa slot j = dn*4+r
    bf16x8 pa;
#pragma unroll
    for (int r = 0; r < 4; ++r) {
      float e0 = __expf(s0[r]);
      float e1 = __expf(s1[r]);
      lp += e0 + e1;
      pa[r] = (bf16)e0;
      pa[4 + r] = (bf16)e1;
    }
    const bf16* vp = vs + (size_t)l15 * 264 + d0 + g * 8;
    __builtin_amdgcn_s_setprio(1);
#pragma unroll
    for (int n = 0; n < 6; ++n) {
      bf16x8 Bv = *(const bf16x8*)(vp + (size_t)n * 16 * 264);
      oacc[n] = MFMA16(pa, Bv, oacc[n]);
    }
    __builtin_amdgcn_s_setprio(0);
  };

#pragma unroll 1
  for (int dt2 = 0; dt2 < 4; ++dt2) {
    attn_step(2 * dt2,     KA, KB, true);
    attn_step(2 * dt2 + 1, KB, KA, 2 * dt2 + 1 < 7);
  }

  // row-sum: lane's lp is a partial for row o = otile+l15; sum across g-groups
  float vsum = lp;
  vsum += __shfl_xor(vsum, 16, 64);
  vsum += __shfl_xor(vsum, 32, 64);
  float inv = 1.0f / vsum;
  // redistribute to D-layout rows: lane needs inv of rows otile + g*4 + r
  float invr[4];
#pragma unroll
  for (int r = 0; r < 4; ++r)
    invr[r] = __shfl(inv, g * 4 + r, 16);

  // ---- epilogue: direct stores. Lane holds rows o = otile+4g+r at
  // w = 16n+l15 -> 24 scalar f32 stores in 64-B coalesced runs. ----
  float* ob = out + (size_t)b * 2359296 + (size_t)h * 96;
#pragma unroll
  for (int n = 0; n < 6; ++n) {
    int w = n * 16 + l15;
#pragma unroll
    for (int r = 0; r < 4; ++r) {
      int o = otile + g * 4 + r;
      ob[(size_t)o * 9216 + w] = oacc[n][r] * invr[r];
    }
  }
}

// ---------------------------------------------------------------------------
extern "C" void kernel_launch(void* const* d_in, const int* in_sizes, int n_in,
                              void* d_out, int out_size, void* d_ws, size_t ws_size,
                              hipStream_t stream) {
  const float* x  = (const float*)d_in[0];
  const float* y  = (const float*)d_in[1];
  const float* wy = (const float*)d_in[2];
  const float* by = (const float*)d_in[3];
  const float* wq = (const float*)d_in[4];
  const float* bq = (const float*)d_in[5];
  const float* wk = (const float*)d_in[6];
  const float* bk = (const float*)d_in[7];
  const float* wv = (const float*)d_in[8];
  const float* bv = (const float*)d_in[9];
  float* out = (float*)d_out;

  char* wsb = (char*)d_ws;
  bf16* wq_bf = (bf16*)(wsb);
  bf16* wk_bf = (bf16*)(wsb + 131072);
  bf16* wv_bf = (bf16*)(wsb + 262144);
  float* yu   = (float*)(wsb + 393216);
  float* aq   = (float*)(wsb + 688128);
  float* cq   = (float*)(wsb + 689152);
  float* ak   = (float*)(wsb + 690176);
  float* ck   = (float*)(wsb + 691200);

  hipLaunchKernelGGL(k_prep, dim3(232), dim3(256), 0, stream,
                     y, wy, by, wq, bq, wk, bk, wv,
                     wq_bf, wk_bf, wv_bf, yu, aq, cq, ak, ck);
  hipLaunchKernelGGL(k_fused, dim3(768), dim3(1024), 0, stream,
                     x, yu, wq_bf, wk_bf, wv_bf, bq, bk, bv,
                     aq, cq, ak, ck, out);
}

// Round 5
// 212.415 us; speedup vs baseline: 1.0177x; 1.0177x over previous
//
#include <hip/hip_runtime.h>

typedef __bf16 bf16;
typedef __attribute__((ext_vector_type(8))) __bf16 bf16x8;
typedef __attribute__((ext_vector_type(4))) __bf16 bf16x4;
typedef __attribute__((ext_vector_type(4))) float f32x4;

#define MFMA16(A, B, C) __builtin_amdgcn_mfma_f32_16x16x32_bf16(A, B, C, 0, 0, 0)

// ---------------------------------------------------------------------------
// k_prep v2: re-parallelized — 224 blocks x 256, single short round.
//   blk   0..95 : weight f32->bf16 cvt (2 float4/thread)
//   blk  96..191: yu bilinear upsample (96 blocks: 8 b x 12 segs, 3 px/thread)
//   blk 192..223: gate coefficients
// ---------------------------------------------------------------------------
__global__ __launch_bounds__(256) void k_prep(
    const float* __restrict__ y, const float* __restrict__ wy, const float* __restrict__ by,
    const float* __restrict__ wq, const float* __restrict__ bq,
    const float* __restrict__ wk, const float* __restrict__ bk,
    const float* __restrict__ wv,
    bf16* __restrict__ wq_bf, bf16* __restrict__ wk_bf, bf16* __restrict__ wv_bf,
    float* __restrict__ yu, float* __restrict__ aq, float* __restrict__ cq,
    float* __restrict__ ak, float* __restrict__ ck)
{
  int blk = blockIdx.x, t = threadIdx.x;
  if (blk < 96) {
#pragma unroll
    for (int rep = 0; rep < 2; ++rep) {
      int idx4 = rep * 24576 + blk * 256 + t;
      int fo = idx4 * 4;
      const float* src; bf16* dst; int off;
      if (fo < 65536)       { src = wq; dst = wq_bf; off = fo; }
      else if (fo < 131072) { src = wk; dst = wk_bf; off = fo - 65536; }
      else                  { src = wv; dst = wv_bf; off = fo - 131072; }
      float4 v = *(const float4*)(src + off);
      bf16x4 o;
      o[0] = (bf16)v.x; o[1] = (bf16)v.y; o[2] = (bf16)v.z; o[3] = (bf16)v.w;
      *(bf16x4*)(dst + off) = o;
    }
  } else if (blk < 192) {
    // bilinear upsample y[b,1,24,24] -> yu[b,96,96], half-pixel, edge clamp
    int blkc = blk - 96;
    int b = blkc / 12, seg = blkc % 12;
    const float* yb = y + b * 576;
#pragma unroll
    for (int i = 0; i < 3; ++i) {
      int e = seg * 768 + i * 256 + t;
      int oh = e / 96, ow = e % 96;
      float sh = oh * 0.25f - 0.375f;
      float sw = ow * 0.25f - 0.375f;
      int ih0 = (int)floorf(sh);
      int iw0 = (int)floorf(sw);
      float fh = sh - (float)ih0, fw = sw - (float)iw0;
      int ih0c = min(23, max(0, ih0)), ih1c = min(23, max(0, ih0 + 1));
      int iw0c = min(23, max(0, iw0)), iw1c = min(23, max(0, iw0 + 1));
      float v00 = yb[ih0c * 24 + iw0c], v01 = yb[ih0c * 24 + iw1c];
      float v10 = yb[ih1c * 24 + iw0c], v11 = yb[ih1c * 24 + iw1c];
      yu[b * 9216 + e] = (1.0f - fh) * ((1.0f - fw) * v00 + fw * v01)
                       + fh * ((1.0f - fw) * v10 + fw * v11);
    }
  } else {
    // gate coefficients: aq = wq*wy, cq = wq*by + bq (same for k)
    int ol = t >> 5, cl = t & 31;
    int o = (blk - 192) * 8 + ol;
    int c0 = cl * 8;
    float4 wy0 = *(const float4*)(wy + c0), wy1 = *(const float4*)(wy + c0 + 4);
    float4 by0 = *(const float4*)(by + c0), by1 = *(const float4*)(by + c0 + 4);
    float4 q0  = *(const float4*)(wq + o * 256 + c0), q1 = *(const float4*)(wq + o * 256 + c0 + 4);
    float4 k0  = *(const float4*)(wk + o * 256 + c0), k1 = *(const float4*)(wk + o * 256 + c0 + 4);
    float wyv[8] = {wy0.x, wy0.y, wy0.z, wy0.w, wy1.x, wy1.y, wy1.z, wy1.w};
    float byv[8] = {by0.x, by0.y, by0.z, by0.w, by1.x, by1.y, by1.z, by1.w};
    float qv[8]  = {q0.x, q0.y, q0.z, q0.w, q1.x, q1.y, q1.z, q1.w};
    float kv[8]  = {k0.x, k0.y, k0.z, k0.w, k1.x, k1.y, k1.z, k1.w};
    float saq = 0.f, scq = 0.f, sak = 0.f, sck = 0.f;
#pragma unroll
    for (int j = 0; j < 8; ++j) {
      saq += qv[j] * wyv[j]; scq += qv[j] * byv[j];
      sak += kv[j] * wyv[j]; sck += kv[j] * byv[j];
    }
#pragma unroll
    for (int s = 16; s >= 1; s >>= 1) {
      saq += __shfl_xor(saq, s, 32);
      scq += __shfl_xor(scq, s, 32);
      sak += __shfl_xor(sak, s, 32);
      sck += __shfl_xor(sck, s, 32);
    }
    if (cl == 0) {
      aq[o] = saq; cq[o] = scq + bq[o];
      ak[o] = sak; ck[o] = sck + bk[o];
    }
  }
}

// ---------------------------------------------------------------------------
// k_fused: one block of 1024 threads (16 waves, 4/SIMD) per (b,h) row.
// Each wave owns one 16-row o/d tile. All intermediates on-chip.
//   LDS: xs [96 w][264 c]   50688 B  (reused as vs [96 w][264 d], d-permuted)
//        ks [256 o][104 w]  53248 B
//   Total 103936 B -> 1 block/CU, 16 waves = 4 waves/SIMD.
// R5: phase 0 split into two c-bands pipelined into the projection loop:
// band A (c<128) -> barrier -> issue band-B global loads to regs -> kq 0-3
// (read only c<128) overlap the loads -> write band B -> barrier -> kq 4-7.
// Everything else identical to R4 (pi-permuted qf/K b64 reads, d-permuted V,
// direct-store epilogue).
// ---------------------------------------------------------------------------
__global__ __launch_bounds__(1024, 1) void k_fused(
    const float* __restrict__ x, const float* __restrict__ yu,
    const bf16* __restrict__ wq_bf, const bf16* __restrict__ wk_bf, const bf16* __restrict__ wv_bf,
    const float* __restrict__ bq, const float* __restrict__ bk, const float* __restrict__ bv,
    const float* __restrict__ aq, const float* __restrict__ cq,
    const float* __restrict__ ak, const float* __restrict__ ck,
    float* __restrict__ out)
{
  __shared__ __align__(16) bf16 xs[96 * 264];             // 50688 B (-> vs)
  __shared__ __align__(16) bf16 ks[256 * 104];            // 53248 B

  int pl = blockIdx.x;
  int b = pl / 96, h = pl % 96;
  int t = threadIdx.x;
  int wid = t >> 6, lane = t & 63;
  int l15 = lane & 15, g = lane >> 4;
  int otile = wid * 16;            // this wave's 16-row o/d tile base

  const float* xrow = x + (size_t)b * 2359296 + (size_t)h * 96;

  // ---- phase 0a: load x band A (c 0..127) -> xs (1536 tasks) ----
#pragma unroll
  for (int rep = 0; rep < 2; ++rep) {
    int task = rep * 1024 + t;
    if (task < 1536) {              // rep==1: waves 8..15 skip (wave-uniform)
      int w = task % 96;
      int c0 = (task / 96) * 8;
      float v[8];
#pragma unroll
      for (int j = 0; j < 8; ++j) v[j] = xrow[(size_t)(c0 + j) * 9216 + w];
      bf16x8 o8;
#pragma unroll
      for (int j = 0; j < 8; ++j) o8[j] = (bf16)v[j];
      *(bf16x8*)(xs + w * 264 + c0) = o8;
    }
  }

  // weight frags for kq=0 issued before the barrier (latency under sync)
  size_t wo0 = (size_t)(otile + l15) * 256 + g * 8;
  bf16x8 Bq_c = *(const bf16x8*)(wq_bf + wo0);
  bf16x8 Bk_c = *(const bf16x8*)(wk_bf + wo0);
  bf16x8 Bv_c = *(const bf16x8*)(wv_bf + wo0);

  __syncthreads();   // band A visible

  const float SC = 0.17677669529663687f;  // 1/sqrt(32), folded into q

  bf16x8 qf[3];   // this wave's 16 o-rows of q, pi-permuted fragment

  // ---- phase 1: q, k AND v projections; band B x-load overlapped ----
  {
    f32x4 qacc[6] = {};
    f32x4 kacc[6] = {};
    f32x4 vacc[6] = {};

    // issue band B (c 128..255) global loads -> regs; they retire under kq 0-3
    float vB0[8], vB1[8];
    int wB0 = t % 96, cB0 = (t / 96) * 8 + 128;
#pragma unroll
    for (int j = 0; j < 8; ++j) vB0[j] = xrow[(size_t)(cB0 + j) * 9216 + wB0];
    int tB1 = 1024 + t;
    int wB1 = tB1 % 96, cB1 = (tB1 / 96) * 8 + 128;
    if (t < 512) {
#pragma unroll
      for (int j = 0; j < 8; ++j) vB1[j] = xrow[(size_t)(cB1 + j) * 9216 + wB1];
    }

#pragma unroll 1
    for (int kq = 0; kq < 4; ++kq) {
      bf16x8 Bq_n, Bk_n, Bv_n;
      {
        size_t wo = wo0 + (kq + 1) * 32;
        Bq_n = *(const bf16x8*)(wq_bf + wo);
        Bk_n = *(const bf16x8*)(wk_bf + wo);
        Bv_n = *(const bf16x8*)(wv_bf + wo);
      }
      const bf16* xp = xs + kq * 32 + g * 8;
      bf16x8 A[6];
#pragma unroll
      for (int m = 0; m < 6; ++m)
        A[m] = *(const bf16x8*)(xp + (m * 16 + l15) * 264);
#pragma unroll
      for (int m = 0; m < 6; ++m) {
        qacc[m] = MFMA16(A[m], Bq_c, qacc[m]);     // D[w][o]  (swapped)
        kacc[m] = MFMA16(A[m], Bk_c, kacc[m]);     // D[w][o]  (swapped)
        vacc[m] = MFMA16(Bv_c, A[m], vacc[m]);     // D[d][w]  (natural)
      }
      Bq_c = Bq_n; Bk_c = Bk_n; Bv_c = Bv_n;
    }

    // write band B to xs, then make it visible
    {
      bf16x8 o8;
#pragma unroll
      for (int j = 0; j < 8; ++j) o8[j] = (bf16)vB0[j];
      *(bf16x8*)(xs + wB0 * 264 + cB0) = o8;
      if (t < 512) {
        bf16x8 o9;
#pragma unroll
        for (int j = 0; j < 8; ++j) o9[j] = (bf16)vB1[j];
        *(bf16x8*)(xs + wB1 * 264 + cB1) = o9;
      }
    }
    __syncthreads();   // band B visible

#pragma unroll 1
    for (int kq = 4; kq < 8; ++kq) {
      bf16x8 Bq_n, Bk_n, Bv_n;
      if (kq < 7) {
        size_t wo = wo0 + (kq + 1) * 32;
        Bq_n = *(const bf16x8*)(wq_bf + wo);
        Bk_n = *(const bf16x8*)(wk_bf + wo);
        Bv_n = *(const bf16x8*)(wv_bf + wo);
      }
      const bf16* xp = xs + kq * 32 + g * 8;
      bf16x8 A[6];
#pragma unroll
      for (int m = 0; m < 6; ++m)
        A[m] = *(const bf16x8*)(xp + (m * 16 + l15) * 264);
#pragma unroll
      for (int m = 0; m < 6; ++m) {
        qacc[m] = MFMA16(A[m], Bq_c, qacc[m]);
        kacc[m] = MFMA16(A[m], Bk_c, kacc[m]);
        vacc[m] = MFMA16(Bv_c, A[m], vacc[m]);
      }
      Bq_c = Bq_n; Bk_c = Bk_n; Bv_c = Bv_n;
    }

    // yu gate values loaded AFTER the MFMA loop (keeps loop VGPR pressure low)
    float4 yv[6];
    {
      const float* yr = yu + (size_t)pl * 96;
#pragma unroll
      for (int mt = 0; mt < 6; ++mt)
        yv[mt] = *(const float4*)(yr + mt * 16 + g * 4);
    }
    int o = otile + l15;
    float bqv = bq[o], aq0 = aq[o], cq0 = cq[o];
    float bkv = bk[o], ak0 = ak[o], ck0 = ck[o];

    // q: gate+scale -> qf DIRECTLY (slot j of chunk kk holds w =
    // 32kk + 16(j>>2) + 4g + (j&3), i.e. qacc[2kk+(j>>2)][j&3]).
#pragma unroll
    for (int kk = 0; kk < 3; ++kk) {
      bf16x8 qq;
#pragma unroll
      for (int jh = 0; jh < 2; ++jh) {
        int m = 2 * kk + jh;
        float yy[4] = {yv[m].x, yv[m].y, yv[m].z, yv[m].w};
#pragma unroll
        for (int r = 0; r < 4; ++r)
          qq[jh * 4 + r] = (bf16)((qacc[m][r] + bqv) * (yy[r] * aq0 + cq0) * SC);
      }
      qf[kk] = qq;
    }

    // k: gate -> ks[o][w] (this wave's 16 rows)
#pragma unroll
    for (int m = 0; m < 6; ++m) {
      float yy[4] = {yv[m].x, yv[m].y, yv[m].z, yv[m].w};
      bf16x4 pk;
#pragma unroll
      for (int r = 0; r < 4; ++r)
        pk[r] = (bf16)((kacc[m][r] + bkv) * (yy[r] * ak0 + ck0));
      *(bf16x4*)(ks + (size_t)o * 104 + m * 16 + g * 4) = pk;
    }

    // v: bias; wait for ALL waves to finish reading xs, then write vs = xs.
    // D-PERMUTED store: d = 32a + dn*16 + g*4 + r placed at
    // pos = 32a + g*8 + dn*4 + r (agrees with pa slot map = pi).
    float4 bm = *(const float4*)(bv + otile + g * 4);
    float bb[4] = {bm.x, bm.y, bm.z, bm.w};
    __syncthreads();   // all xs reads done block-wide
    bf16* vs = xs;     // reuse xs as vs[w][264 dpos]
    int vbase = (otile & ~16) + ((otile >> 2) & 4);   // 32a + dn*4
#pragma unroll
    for (int n = 0; n < 6; ++n) {
      bf16x4 pk;
#pragma unroll
      for (int r = 0; r < 4; ++r) pk[r] = (bf16)(vacc[n][r] + bb[r]);
      *(bf16x4*)(vs + (size_t)(n * 16 + l15) * 264 + vbase + g * 8) = pk;
    }
  }
  __syncthreads();     // ks + vs visible to all waves

  // ---- phase 4: swapped scores -> in-register P -> out = P*v ----
  const bf16* vs = xs;
  f32x4 oacc[6] = {};
  float lp = 0.f;

  // K fragment loader with the pi slot-permutation: slot j of chunk kk =
  // ks[d][32kk + 16(j>>2) + 4g + (j&3)] -> two b64 reads 32 B apart.
  auto load_K = [&](int dt, bf16x8* K) {
    const bf16* kp = ks + (size_t)(dt * 32 + l15) * 104 + g * 4;
#pragma unroll
    for (int kk = 0; kk < 3; ++kk)
#pragma unroll
      for (int dn = 0; dn < 2; ++dn) {
        const bf16* p = kp + (size_t)(dn * 16) * 104 + kk * 32;
        bf16x4 lo = *(const bf16x4*)(p);
        bf16x4 hi = *(const bf16x4*)(p + 16);
        K[kk * 2 + dn] = __builtin_shufflevector(lo, hi, 0, 1, 2, 3, 4, 5, 6, 7);
      }
  };

  bf16x8 KA[6], KB[6];   // K-fragment double-buffer (regs)
  load_K(0, KA);

  auto attn_step = [&](int dt, bf16x8* Kc, bf16x8* Kn, bool pf) {
    int d0 = dt * 32;
    // prefetch next dt's K-fragments (independent; overlaps QK+exp+PV)
    if (pf) load_K(dt + 1, Kn);
    f32x4 s0 = {}, s1 = {};
    __builtin_amdgcn_s_setprio(1);
#pragma unroll
    for (int kk = 0; kk < 3; ++kk) {
      s0 = MFMA16(Kc[kk * 2 + 0], qf[kk], s0);   // D[m=d][n=o]
      s1 = MFMA16(Kc[kk * 2 + 1], qf[kk], s1);
    }
    __builtin_amdgcn_s_setprio(0);
    // lane holds P[o=otile+l15][d0 + dn*16 + g*4 + r] -> pa slot j = dn*4+r
    bf16x8 pa;
#pragma unroll
    for (int r = 0; r < 4; ++r) {
      float e0 = __expf(s0[r]);
      float e1 = __expf(s1[r]);
      lp += e0 + e1;
      pa[r] = (bf16)e0;
      pa[4 + r] = (bf16)e1;
    }
    const bf16* vp = vs + (size_t)l15 * 264 + d0 + g * 8;
    __builtin_amdgcn_s_setprio(1);
#pragma unroll
    for (int n = 0; n < 6; ++n) {
      bf16x8 Bv = *(const bf16x8*)(vp + (size_t)n * 16 * 264);
      oacc[n] = MFMA16(pa, Bv, oacc[n]);
    }
    __builtin_amdgcn_s_setprio(0);
  };

#pragma unroll 1
  for (int dt2 = 0; dt2 < 4; ++dt2) {
    attn_step(2 * dt2,     KA, KB, true);
    attn_step(2 * dt2 + 1, KB, KA, 2 * dt2 + 1 < 7);
  }

  // row-sum: lane's lp is a partial for row o = otile+l15; sum across g-groups
  float vsum = lp;
  vsum += __shfl_xor(vsum, 16, 64);
  vsum += __shfl_xor(vsum, 32, 64);
  float inv = 1.0f / vsum;
  // redistribute to D-layout rows: lane needs inv of rows otile + g*4 + r
  float invr[4];
#pragma unroll
  for (int r = 0; r < 4; ++r)
    invr[r] = __shfl(inv, g * 4 + r, 16);

  // ---- epilogue: direct stores. Lane holds rows o = otile+4g+r at
  // w = 16n+l15 -> 24 scalar f32 stores in 64-B coalesced runs. ----
  float* ob = out + (size_t)b * 2359296 + (size_t)h * 96;
#pragma unroll
  for (int n = 0; n < 6; ++n) {
    int w = n * 16 + l15;
#pragma unroll
    for (int r = 0; r < 4; ++r) {
      int o = otile + g * 4 + r;
      ob[(size_t)o * 9216 + w] = oacc[n][r] * invr[r];
    }
  }
}

// ---------------------------------------------------------------------------
extern "C" void kernel_launch(void* const* d_in, const int* in_sizes, int n_in,
                              void* d_out, int out_size, void* d_ws, size_t ws_size,
                              hipStream_t stream) {
  const float* x  = (const float*)d_in[0];
  const float* y  = (const float*)d_in[1];
  const float* wy = (const float*)d_in[2];
  const float* by = (const float*)d_in[3];
  const float* wq = (const float*)d_in[4];
  const float* bq = (const float*)d_in[5];
  const float* wk = (const float*)d_in[6];
  const float* bk = (const float*)d_in[7];
  const float* wv = (const float*)d_in[8];
  const float* bv = (const float*)d_in[9];
  float* out = (float*)d_out;

  char* wsb = (char*)d_ws;
  bf16* wq_bf = (bf16*)(wsb);
  bf16* wk_bf = (bf16*)(wsb + 131072);
  bf16* wv_bf = (bf16*)(wsb + 262144);
  float* yu   = (float*)(wsb + 393216);
  float* aq   = (float*)(wsb + 688128);
  float* cq   = (float*)(wsb + 689152);
  float* ak   = (float*)(wsb + 690176);
  float* ck   = (float*)(wsb + 691200);

  hipLaunchKernelGGL(k_prep, dim3(224), dim3(256), 0, stream,
                     y, wy, by, wq, bq, wk, bk, wv,
                     wq_bf, wk_bf, wv_bf, yu, aq, cq, ak, ck);
  hipLaunchKernelGGL(k_fused, dim3(768), dim3(1024), 0, stream,
                     x, yu, wq_bf, wk_bf, wv_bf, bq, bk, bv,
                     aq, cq, ak, ck, out);
}

// Round 6
// 211.511 us; speedup vs baseline: 1.0221x; 1.0043x over previous
//
#include <hip/hip_runtime.h>

typedef __bf16 bf16;
typedef __attribute__((ext_vector_type(8))) __bf16 bf16x8;
typedef __attribute__((ext_vector_type(4))) __bf16 bf16x4;
typedef __attribute__((ext_vector_type(4))) float f32x4;

#define MFMA16(A, B, C) __builtin_amdgcn_mfma_f32_16x16x32_bf16(A, B, C, 0, 0, 0)

// ---------------------------------------------------------------------------
// k_prep v2: re-parallelized — 224 blocks x 256, single short round.
//   blk   0..95 : weight f32->bf16 cvt (2 float4/thread)
//   blk  96..191: yu bilinear upsample (96 blocks: 8 b x 12 segs, 3 px/thread)
//   blk 192..223: gate coefficients
// ---------------------------------------------------------------------------
__global__ __launch_bounds__(256) void k_prep(
    const float* __restrict__ y, const float* __restrict__ wy, const float* __restrict__ by,
    const float* __restrict__ wq, const float* __restrict__ bq,
    const float* __restrict__ wk, const float* __restrict__ bk,
    const float* __restrict__ wv,
    bf16* __restrict__ wq_bf, bf16* __restrict__ wk_bf, bf16* __restrict__ wv_bf,
    float* __restrict__ yu, float* __restrict__ aq, float* __restrict__ cq,
    float* __restrict__ ak, float* __restrict__ ck)
{
  int blk = blockIdx.x, t = threadIdx.x;
  if (blk < 96) {
#pragma unroll
    for (int rep = 0; rep < 2; ++rep) {
      int idx4 = rep * 24576 + blk * 256 + t;
      int fo = idx4 * 4;
      const float* src; bf16* dst; int off;
      if (fo < 65536)       { src = wq; dst = wq_bf; off = fo; }
      else if (fo < 131072) { src = wk; dst = wk_bf; off = fo - 65536; }
      else                  { src = wv; dst = wv_bf; off = fo - 131072; }
      float4 v = *(const float4*)(src + off);
      bf16x4 o;
      o[0] = (bf16)v.x; o[1] = (bf16)v.y; o[2] = (bf16)v.z; o[3] = (bf16)v.w;
      *(bf16x4*)(dst + off) = o;
    }
  } else if (blk < 192) {
    // bilinear upsample y[b,1,24,24] -> yu[b,96,96], half-pixel, edge clamp
    int blkc = blk - 96;
    int b = blkc / 12, seg = blkc % 12;
    const float* yb = y + b * 576;
#pragma unroll
    for (int i = 0; i < 3; ++i) {
      int e = seg * 768 + i * 256 + t;
      int oh = e / 96, ow = e % 96;
      float sh = oh * 0.25f - 0.375f;
      float sw = ow * 0.25f - 0.375f;
      int ih0 = (int)floorf(sh);
      int iw0 = (int)floorf(sw);
      float fh = sh - (float)ih0, fw = sw - (float)iw0;
      int ih0c = min(23, max(0, ih0)), ih1c = min(23, max(0, ih0 + 1));
      int iw0c = min(23, max(0, iw0)), iw1c = min(23, max(0, iw0 + 1));
      float v00 = yb[ih0c * 24 + iw0c], v01 = yb[ih0c * 24 + iw1c];
      float v10 = yb[ih1c * 24 + iw0c], v11 = yb[ih1c * 24 + iw1c];
      yu[b * 9216 + e] = (1.0f - fh) * ((1.0f - fw) * v00 + fw * v01)
                       + fh * ((1.0f - fw) * v10 + fw * v11);
    }
  } else {
    // gate coefficients: aq = wq*wy, cq = wq*by + bq (same for k)
    int ol = t >> 5, cl = t & 31;
    int o = (blk - 192) * 8 + ol;
    int c0 = cl * 8;
    float4 wy0 = *(const float4*)(wy + c0), wy1 = *(const float4*)(wy + c0 + 4);
    float4 by0 = *(const float4*)(by + c0), by1 = *(const float4*)(by + c0 + 4);
    float4 q0  = *(const float4*)(wq + o * 256 + c0), q1 = *(const float4*)(wq + o * 256 + c0 + 4);
    float4 k0  = *(const float4*)(wk + o * 256 + c0), k1 = *(const float4*)(wk + o * 256 + c0 + 4);
    float wyv[8] = {wy0.x, wy0.y, wy0.z, wy0.w, wy1.x, wy1.y, wy1.z, wy1.w};
    float byv[8] = {by0.x, by0.y, by0.z, by0.w, by1.x, by1.y, by1.z, by1.w};
    float qv[8]  = {q0.x, q0.y, q0.z, q0.w, q1.x, q1.y, q1.z, q1.w};
    float kv[8]  = {k0.x, k0.y, k0.z, k0.w, k1.x, k1.y, k1.z, k1.w};
    float saq = 0.f, scq = 0.f, sak = 0.f, sck = 0.f;
#pragma unroll
    for (int j = 0; j < 8; ++j) {
      saq += qv[j] * wyv[j]; scq += qv[j] * byv[j];
      sak += kv[j] * wyv[j]; sck += kv[j] * byv[j];
    }
#pragma unroll
    for (int s = 16; s >= 1; s >>= 1) {
      saq += __shfl_xor(saq, s, 32);
      scq += __shfl_xor(scq, s, 32);
      sak += __shfl_xor(sak, s, 32);
      sck += __shfl_xor(sck, s, 32);
    }
    if (cl == 0) {
      aq[o] = saq; cq[o] = scq + bq[o];
      ak[o] = sak; ck[o] = sck + bk[o];
    }
  }
}

// ---------------------------------------------------------------------------
// k_fused: one block of 1024 threads (16 waves, 4/SIMD) per (b,h) row.
// Each wave owns one 16-row o/d tile. All intermediates on-chip.
//   LDS: xs [96 w][264 c]   50688 B  (reused as vs [96 w][264 d], d-permuted)
//        ks [256 o][104 w]  53248 B
//   Total 103936 B -> 1 block/CU, 16 waves = 4 waves/SIMD.
// R6: (1) band-B register pipelining REVERTED (R5 counters showed scratch
// spill: WRITE +12.3MB / FETCH +6MB). (2) per-wave loop staggering: P1
// iterates kq = (s+i)&7 and P4 dt = (s+i)&7 with s = (wid+(wid>>2))&7 so
// SIMD-mates sit in different phases (exp vs MFMA vs LDS) instead of
// convoying through identical instruction streams after each barrier.
// All accumulators are order-independent sums; prefetches wrap mod 8.
// ---------------------------------------------------------------------------
__global__ __launch_bounds__(1024, 1) void k_fused(
    const float* __restrict__ x, const float* __restrict__ yu,
    const bf16* __restrict__ wq_bf, const bf16* __restrict__ wk_bf, const bf16* __restrict__ wv_bf,
    const float* __restrict__ bq, const float* __restrict__ bk, const float* __restrict__ bv,
    const float* __restrict__ aq, const float* __restrict__ cq,
    const float* __restrict__ ak, const float* __restrict__ ck,
    float* __restrict__ out)
{
  __shared__ __align__(16) bf16 xs[96 * 264];             // 50688 B (-> vs)
  __shared__ __align__(16) bf16 ks[256 * 104];            // 53248 B

  int pl = blockIdx.x;
  int b = pl / 96, h = pl % 96;
  int t = threadIdx.x;
  int wid = t >> 6, lane = t & 63;
  int l15 = lane & 15, g = lane >> 4;
  int otile = wid * 16;            // this wave's 16-row o/d tile base
  int s8 = (wid + (wid >> 2)) & 7; // per-wave stagger start (distinct on SIMD)

  const float* xrow = x + (size_t)b * 2359296 + (size_t)h * 96;

  // ---- phase 0: load x[b,:,h,:] -> xs[w][c] (bf16) ----
#pragma unroll
  for (int i = 0; i < 3; ++i) {
    int tsk = i * 1024 + t;       // 96 w x 32 cgroups
    int w = tsk % 96;
    int c0 = (tsk / 96) * 8;
    float v[8];
#pragma unroll
    for (int j = 0; j < 8; ++j) v[j] = xrow[(size_t)(c0 + j) * 9216 + w];
    bf16x8 o8;
#pragma unroll
    for (int j = 0; j < 8; ++j) o8[j] = (bf16)v[j];
    *(bf16x8*)(xs + w * 264 + c0) = o8;
  }

  // weight frags for this wave's FIRST kq (= s8) issued before the barrier
  size_t wo0 = (size_t)(otile + l15) * 256 + g * 8;
  bf16x8 Bq_c = *(const bf16x8*)(wq_bf + wo0 + s8 * 32);
  bf16x8 Bk_c = *(const bf16x8*)(wk_bf + wo0 + s8 * 32);
  bf16x8 Bv_c = *(const bf16x8*)(wv_bf + wo0 + s8 * 32);

  __syncthreads();

  const float SC = 0.17677669529663687f;  // 1/sqrt(32), folded into q

  bf16x8 qf[3];   // this wave's 16 o-rows of q, pi-permuted fragment

  // ---- phase 1: q, k AND v projections in one staggered pass over xs ----
  // Per step: 6 LDS A-frags + 3 (pipelined) global weight frags -> 18 MFMAs.
  {
    f32x4 qacc[6] = {};
    f32x4 kacc[6] = {};
    f32x4 vacc[6] = {};
#pragma unroll 1
    for (int i = 0; i < 8; ++i) {
      int kq = (s8 + i) & 7;
      // prefetch next step's weight frags (independent of this iteration)
      bf16x8 Bq_n, Bk_n, Bv_n;
      if (i < 7) {
        size_t wo = wo0 + (size_t)(((s8 + i + 1) & 7) * 32);
        Bq_n = *(const bf16x8*)(wq_bf + wo);
        Bk_n = *(const bf16x8*)(wk_bf + wo);
        Bv_n = *(const bf16x8*)(wv_bf + wo);
      }
      const bf16* xp = xs + kq * 32 + g * 8;
      bf16x8 A[6];
#pragma unroll
      for (int m = 0; m < 6; ++m)
        A[m] = *(const bf16x8*)(xp + (m * 16 + l15) * 264);
#pragma unroll
      for (int m = 0; m < 6; ++m) {
        qacc[m] = MFMA16(A[m], Bq_c, qacc[m]);     // D[w][o]  (swapped)
        kacc[m] = MFMA16(A[m], Bk_c, kacc[m]);     // D[w][o]  (swapped)
        vacc[m] = MFMA16(Bv_c, A[m], vacc[m]);     // D[d][w]  (natural)
      }
      Bq_c = Bq_n; Bk_c = Bk_n; Bv_c = Bv_n;
    }

    // yu gate values loaded AFTER the MFMA loop (keeps loop VGPR pressure low)
    float4 yv[6];
    {
      const float* yr = yu + (size_t)pl * 96;
#pragma unroll
      for (int mt = 0; mt < 6; ++mt)
        yv[mt] = *(const float4*)(yr + mt * 16 + g * 4);
    }
    int o = otile + l15;
    float bqv = bq[o], aq0 = aq[o], cq0 = cq[o];
    float bkv = bk[o], ak0 = ak[o], ck0 = ck[o];

    // q: gate+scale -> qf DIRECTLY (slot j of chunk kk holds w =
    // 32kk + 16(j>>2) + 4g + (j&3), i.e. qacc[2kk+(j>>2)][j&3]).
#pragma unroll
    for (int kk = 0; kk < 3; ++kk) {
      bf16x8 qq;
#pragma unroll
      for (int jh = 0; jh < 2; ++jh) {
        int m = 2 * kk + jh;
        float yy[4] = {yv[m].x, yv[m].y, yv[m].z, yv[m].w};
#pragma unroll
        for (int r = 0; r < 4; ++r)
          qq[jh * 4 + r] = (bf16)((qacc[m][r] + bqv) * (yy[r] * aq0 + cq0) * SC);
      }
      qf[kk] = qq;
    }

    // k: gate -> ks[o][w] (this wave's 16 rows)
#pragma unroll
    for (int m = 0; m < 6; ++m) {
      float yy[4] = {yv[m].x, yv[m].y, yv[m].z, yv[m].w};
      bf16x4 pk;
#pragma unroll
      for (int r = 0; r < 4; ++r)
        pk[r] = (bf16)((kacc[m][r] + bkv) * (yy[r] * ak0 + ck0));
      *(bf16x4*)(ks + (size_t)o * 104 + m * 16 + g * 4) = pk;
    }

    // v: bias; wait for ALL waves to finish reading xs, then write vs = xs.
    // D-PERMUTED store: d = 32a + dn*16 + g*4 + r placed at
    // pos = 32a + g*8 + dn*4 + r (agrees with pa slot map = pi).
    float4 bm = *(const float4*)(bv + otile + g * 4);
    float bb[4] = {bm.x, bm.y, bm.z, bm.w};
    __syncthreads();   // all xs reads done block-wide
    bf16* vs = xs;     // reuse xs as vs[w][264 dpos]
    int vbase = (otile & ~16) + ((otile >> 2) & 4);   // 32a + dn*4
#pragma unroll
    for (int n = 0; n < 6; ++n) {
      bf16x4 pk;
#pragma unroll
      for (int r = 0; r < 4; ++r) pk[r] = (bf16)(vacc[n][r] + bb[r]);
      *(bf16x4*)(vs + (size_t)(n * 16 + l15) * 264 + vbase + g * 8) = pk;
    }
  }
  __syncthreads();     // ks + vs visible to all waves

  // ---- phase 4: swapped scores -> in-register P -> out = P*v (staggered) ----
  const bf16* vs = xs;
  f32x4 oacc[6] = {};
  float lp = 0.f;

  // K fragment loader with the pi slot-permutation: slot j of chunk kk =
  // ks[d][32kk + 16(j>>2) + 4g + (j&3)] -> two b64 reads 32 B apart.
  auto load_K = [&](int dt, bf16x8* K) {
    const bf16* kp = ks + (size_t)(dt * 32 + l15) * 104 + g * 4;
#pragma unroll
    for (int kk = 0; kk < 3; ++kk)
#pragma unroll
      for (int dn = 0; dn < 2; ++dn) {
        const bf16* p = kp + (size_t)(dn * 16) * 104 + kk * 32;
        bf16x4 lo = *(const bf16x4*)(p);
        bf16x4 hi = *(const bf16x4*)(p + 16);
        K[kk * 2 + dn] = __builtin_shufflevector(lo, hi, 0, 1, 2, 3, 4, 5, 6, 7);
      }
  };

  bf16x8 KA[6], KB[6];   // K-fragment double-buffer (regs)
  load_K(s8, KA);

  auto attn_step = [&](int dt, bf16x8* Kc, bf16x8* Kn, bool pf) {
    int d0 = dt * 32;
    // prefetch next step's K-fragments (independent; overlaps QK+exp+PV)
    if (pf) load_K((dt + 1) & 7, Kn);
    f32x4 s0 = {}, s1 = {};
    __builtin_amdgcn_s_setprio(1);
#pragma unroll
    for (int kk = 0; kk < 3; ++kk) {
      s0 = MFMA16(Kc[kk * 2 + 0], qf[kk], s0);   // D[m=d][n=o]
      s1 = MFMA16(Kc[kk * 2 + 1], qf[kk], s1);
    }
    __builtin_amdgcn_s_setprio(0);
    // lane holds P[o=otile+l15][d0 + dn*16 + g*4 + r] -> pa slot j = dn*4+r
    bf16x8 pa;
#pragma unroll
    for (int r = 0; r < 4; ++r) {
      float e0 = __expf(s0[r]);
      float e1 = __expf(s1[r]);
      lp += e0 + e1;
      pa[r] = (bf16)e0;
      pa[4 + r] = (bf16)e1;
    }
    const bf16* vp = vs + (size_t)l15 * 264 + d0 + g * 8;
    __builtin_amdgcn_s_setprio(1);
#pragma unroll
    for (int n = 0; n < 6; ++n) {
      bf16x8 Bv = *(const bf16x8*)(vp + (size_t)n * 16 * 264);
      oacc[n] = MFMA16(pa, Bv, oacc[n]);
    }
    __builtin_amdgcn_s_setprio(0);
  };

#pragma unroll 1
  for (int i2 = 0; i2 < 4; ++i2) {
    attn_step((s8 + 2 * i2) & 7,     KA, KB, true);
    attn_step((s8 + 2 * i2 + 1) & 7, KB, KA, 2 * i2 + 1 < 7);
  }

  // row-sum: lane's lp is a partial for row o = otile+l15; sum across g-groups
  float vsum = lp;
  vsum += __shfl_xor(vsum, 16, 64);
  vsum += __shfl_xor(vsum, 32, 64);
  float inv = 1.0f / vsum;
  // redistribute to D-layout rows: lane needs inv of rows otile + g*4 + r
  float invr[4];
#pragma unroll
  for (int r = 0; r < 4; ++r)
    invr[r] = __shfl(inv, g * 4 + r, 16);

  // ---- epilogue: direct stores. Lane holds rows o = otile+4g+r at
  // w = 16n+l15 -> 24 scalar f32 stores in 64-B coalesced runs. ----
  float* ob = out + (size_t)b * 2359296 + (size_t)h * 96;
#pragma unroll
  for (int n = 0; n < 6; ++n) {
    int w = n * 16 + l15;
#pragma unroll
    for (int r = 0; r < 4; ++r) {
      int o = otile + g * 4 + r;
      ob[(size_t)o * 9216 + w] = oacc[n][r] * invr[r];
    }
  }
}

// ---------------------------------------------------------------------------
extern "C" void kernel_launch(void* const* d_in, const int* in_sizes, int n_in,
                              void* d_out, int out_size, void* d_ws, size_t ws_size,
                              hipStream_t stream) {
  const float* x  = (const float*)d_in[0];
  const float* y  = (const float*)d_in[1];
  const float* wy = (const float*)d_in[2];
  const float* by = (const float*)d_in[3];
  const float* wq = (const float*)d_in[4];
  const float* bq = (const float*)d_in[5];
  const float* wk = (const float*)d_in[6];
  const float* bk = (const float*)d_in[7];
  const float* wv = (const float*)d_in[8];
  const float* bv = (const float*)d_in[9];
  float* out = (float*)d_out;

  char* wsb = (char*)d_ws;
  bf16* wq_bf = (bf16*)(wsb);
  bf16* wk_bf = (bf16*)(wsb + 131072);
  bf16* wv_bf = (bf16*)(wsb + 262144);
  float* yu   = (float*)(wsb + 393216);
  float* aq   = (float*)(wsb + 688128);
  float* cq   = (float*)(wsb + 689152);
  float* ak   = (float*)(wsb + 690176);
  float* ck   = (float*)(wsb + 691200);

  hipLaunchKernelGGL(k_prep, dim3(224), dim3(256), 0, stream,
                     y, wy, by, wq, bq, wk, bk, wv,
                     wq_bf, wk_bf, wv_bf, yu, aq, cq, ak, ck);
  hipLaunchKernelGGL(k_fused, dim3(768), dim3(1024), 0, stream,
                     x, yu, wq_bf, wk_bf, wv_bf, bq, bk, bv,
                     aq, cq, ak, ck, out);
}